// Round 6
// baseline (4267.147 us; speedup 1.0000x reference)
//
#include <hip/hip_runtime.h>

// AttentionRNN: B=1024, T=256, U=256.
//  Xh = fp16(X) once; P[t] = x_t @ [Wemb|Wre|Wnew] (fp16 MFMA GEMM, CT=16 chunks
//  so P stays L3-resident between GEMM and recurrent). Recurrent: 64 blocks x
//  16 rows x 8 waves; qg = state @ [Wsk|Wrs] via MFMA; P is read EXACTLY ONCE
//  per element into rolling registers; barriers are lgkmcnt-only (P loads stay
//  in flight across phases). P slabs for t=-2,-1 zeroed (no branches).

typedef _Float16 f16;
typedef _Float16 f16x8 __attribute__((ext_vector_type(8)));
typedef _Float16 f16x4 __attribute__((ext_vector_type(4)));
typedef float f32x4 __attribute__((ext_vector_type(4)));

static __device__ __forceinline__ f32x4 mfma16(f16x8 a, f16x8 b, f32x4 c){
  return __builtin_amdgcn_mfma_f32_16x16x32_f16(a, b, c, 0, 0, 0);
}
static __device__ __forceinline__ float sigmoid_f(float x){
  return 1.0f / (1.0f + __expf(-x));
}
static __device__ __forceinline__ float tanh_f(float x){
  float e = __expf(2.0f * x);
  return 1.0f - 2.0f / (e + 1.0f);   // stable
}
// Block barrier that drains LDS ops only; wave-private global loads stay in flight.
static __device__ __forceinline__ void lgkm_barrier(){
  asm volatile("s_waitcnt lgkmcnt(0)" ::: "memory");
  __builtin_amdgcn_s_barrier();
}

// ---------------- cast X fp32 -> fp16 (same layout) ----------------
__global__ void cast_x_kernel(const float* __restrict__ X, f16* __restrict__ Xh){
  size_t e = ((size_t)blockIdx.x * 256 + threadIdx.x) * 8;
  f32x4 v0 = *(const f32x4*)(X + e);
  f32x4 v1 = *(const f32x4*)(X + e + 4);
  f16x8 h;
  #pragma unroll
  for (int j = 0; j < 8; ++j) h[j] = (f16)((j < 4) ? v0[j] : v1[j-4]);
  *(f16x8*)(Xh + e) = h;
}

// ------------- cast weights to fp16 -------------
// WcatT rows: [0,256) Wemb^T, [256,1024) Wre^T, [1024,1792) Wnew^T  (N x K row-major)
// WsrF fragment-packed [ct64][kt8][lane64][e8]: col=ct*16+(lane&15), k=kt*32+((lane>>4)&3)*8+e
__global__ void cast_w_kernel(const float* __restrict__ EK, const float* __restrict__ RE,
    const float* __restrict__ NW, const float* __restrict__ SK, const float* __restrict__ RS,
    f16* __restrict__ WcatT, f16* __restrict__ WsrF){
  int tid = blockIdx.x * 256 + threadIdx.x;
  if (tid < 458752){
    int n = tid >> 8, k = tid & 255;
    float v;
    if (n < 256)       v = EK[k*256 + n];
    else if (n < 1024) v = RE[k*768 + (n-256)];
    else               v = NW[k*768 + (n-1024)];
    WcatT[n*256 + k] = (f16)v;
  } else {
    int idx = tid - 458752;            // 0..262143
    int e    = idx & 7;
    int lane = (idx >> 3) & 63;
    int kt   = (idx >> 9) & 7;
    int ct   = idx >> 12;              // 0..63
    int col  = ct*16 + (lane & 15);
    int k    = kt*32 + ((lane >> 4) & 3)*8 + e;
    float v = (col < 256) ? SK[k*256 + col] : RS[k*768 + (col-256)];
    WsrF[idx] = (f16)v;
  }
}

// ---- GEMM: C[r=tsl*1024+b][0:1792) = Xh[b][t_start+tsl][:] @ WcatT^T ----
__global__ __launch_bounds__(256, 2) void gemm_f16_kernel(
    const f16* __restrict__ Xh, const f16* __restrict__ Bm,
    f16* __restrict__ C, int Mtiles, int t_start)
{
  __shared__ f16 As[128*64];
  __shared__ f16 Bs[128*64];
  const int NT = 14;
  const int nwg = Mtiles * NT;
  int bid = blockIdx.x, wg = bid;
  if ((nwg & 7) == 0){ int cpx = nwg >> 3; wg = (bid & 7) * cpx + (bid >> 3); }
  const int mt = wg / NT, nt = wg % NT;
  const int tsl = mt >> 3;
  const int b0  = (mt & 7) * 128;
  const int t   = t_start + tsl;
  const int n0  = nt * 128;
  const int tid = threadIdx.x;
  const int l = tid & 63, wid = tid >> 6;
  const int wr = wid >> 1, wc = wid & 1;
  const int srow = tid >> 3;
  const int scol = (tid & 7) * 8;

  const size_t ASTR = 32ull * 65536ull;   // 32 b-rows in f16 elems (T*U = 65536)
  const f16* Ab = Xh + ((size_t)(b0 + srow) * 256 + t) * 256 + scol;
  const f16* Bb = Bm + ((size_t)(n0 + srow)) * 256 + scol;

  f16x8 ra[4], rb[4];
  #pragma unroll
  for (int j = 0; j < 4; ++j){
    ra[j] = *(const f16x8*)(Ab + (size_t)j * ASTR);
    rb[j] = *(const f16x8*)(Bb + (size_t)j * 32 * 256);
  }

  f32x4 acc[4][4];
  #pragma unroll
  for (int mi = 0; mi < 4; ++mi)
    #pragma unroll
    for (int ni = 0; ni < 4; ++ni)
      acc[mi][ni] = (f32x4){0.f,0.f,0.f,0.f};

  for (int kt = 0; kt < 4; ++kt){
    #pragma unroll
    for (int j = 0; j < 4; ++j){
      int row = srow + j*32;
      int e = (row*64 + scol) ^ ((row & 7) << 3);
      *(f16x8*)&As[e] = ra[j];
      *(f16x8*)&Bs[e] = rb[j];
    }
    __syncthreads();
    if (kt < 3){
      #pragma unroll
      for (int j = 0; j < 4; ++j){
        ra[j] = *(const f16x8*)(Ab + (kt+1)*64 + (size_t)j * ASTR);
        rb[j] = *(const f16x8*)(Bb + (kt+1)*64 + (size_t)j * 32 * 256);
      }
    }
    #pragma unroll
    for (int kk = 0; kk < 2; ++kk){
      f16x8 af[4], bfr[4];
      #pragma unroll
      for (int mi = 0; mi < 4; ++mi){
        int row = wr*64 + mi*16 + (l & 15);
        int e = (row*64 + kk*32 + (l >> 4)*8) ^ ((row & 7) << 3);
        af[mi] = *(const f16x8*)&As[e];
      }
      #pragma unroll
      for (int ni = 0; ni < 4; ++ni){
        int row = wc*64 + ni*16 + (l & 15);
        int e = (row*64 + kk*32 + (l >> 4)*8) ^ ((row & 7) << 3);
        bfr[ni] = *(const f16x8*)&Bs[e];
      }
      #pragma unroll
      for (int mi = 0; mi < 4; ++mi)
        #pragma unroll
        for (int ni = 0; ni < 4; ++ni)
          acc[mi][ni] = mfma16(af[mi], bfr[ni], acc[mi][ni]);
    }
    __syncthreads();
  }
  const size_t m0 = (size_t)mt * 128;
  #pragma unroll
  for (int mi = 0; mi < 4; ++mi){
    #pragma unroll
    for (int ni = 0; ni < 4; ++ni){
      int col = n0 + wc*64 + ni*16 + (l & 15);
      size_t row = m0 + wr*64 + mi*16 + ((l >> 4) * 4);
      #pragma unroll
      for (int j = 0; j < 4; ++j)
        C[(row + j) * 1792 + col] = (f16)acc[mi][ni][j];
    }
  }
}

// ---------- recurrent: 64 blocks x 16 rows, 512 threads (8 waves) ----------
// wave w: qg cols [w*128,(w+1)*128) in MFMA phase; owns rows 2w,2w+1 for
// scores (half-wave each) + GRU. Rolling registers carry P values forward so
// each P element is loaded exactly once.
__global__ __launch_bounds__(512, 2) void recurrent_kernel(
    const f16* __restrict__ P, const f16* __restrict__ WsrF,
    const float* __restrict__ bias, const float* __restrict__ Lk,
    float* __restrict__ state, float* __restrict__ out,
    int t0, int nsteps)
{
  __shared__ float qg[16*1026];     // [16 rows][1024 cols] (query | gs), pad 2
  __shared__ f16  stA[8*520];       // state f16, fragment-major [kt][lane][8] + pad

  const int tid = threadIdx.x;
  const int l = tid & 63, w = tid >> 6;          // 8 waves
  const int r0 = blockIdx.x * 16;
  const int arow = l & 15, agrp = l >> 4;        // MFMA fragment mapping
  const int c4 = l * 4;                          // GRU: 4 cols/lane
  const int rA = 2*w, rB = 2*w + 1;
  const int gbA = r0 + rA, gbB = r0 + rB;
  const int srow = 2*w + (l >> 5);               // scores: half-wave per row
  const int sgb  = r0 + srow;
  const int sc0  = (l & 31) * 8;

  const f32x4 sb0 = *(const f32x4*)(bias + sc0);
  const f32x4 sb1 = *(const f32x4*)(bias + sc0 + 4);
  const f32x4 sl0 = *(const f32x4*)(Lk + sc0);
  const f32x4 sl1 = *(const f32x4*)(Lk + sc0 + 4);

  f32x4 snA = *(const f32x4*)(state + (size_t)gbA*256 + c4);
  f32x4 snB = *(const f32x4*)(state + (size_t)gbB*256 + c4);

  f16* const saA = &stA[(l >> 3)*520 + ((((l >> 1) & 3) << 4) + rA)*8 + (l & 1)*4];
  f16* const saB = saA + 8;
  { f16x4 h; h[0]=(f16)snA[0]; h[1]=(f16)snA[1]; h[2]=(f16)snA[2]; h[3]=(f16)snA[3]; *(f16x4*)saA = h; }
  { f16x4 h; h[0]=(f16)snB[0]; h[1]=(f16)snB[1]; h[2]=(f16)snB[2]; h[3]=(f16)snB[3]; *(f16x4*)saB = h; }

  // prologue: rolling registers from slabs 0 (t0-2) and 1 (t0-1)
  const size_t SL = 1024ull*1792ull;
  f16x8 E0 = *(const f16x8*)(P + (size_t)sgb*1792 + sc0);
  f16x8 E1 = *(const f16x8*)(P + SL + (size_t)sgb*1792 + sc0);
  const f16* pA0 = P + (size_t)gbA*1792;
  const f16* pB0 = P + (size_t)gbB*1792;
  f16x4 U2A=*(const f16x4*)(pA0+256+c4), R2A=*(const f16x4*)(pA0+512+c4), C2A=*(const f16x4*)(pA0+768+c4);
  f16x4 U2B=*(const f16x4*)(pB0+256+c4), R2B=*(const f16x4*)(pB0+512+c4), C2B=*(const f16x4*)(pB0+768+c4);
  f16x4 U1A=*(const f16x4*)(pA0+SL+256+c4), R1A=*(const f16x4*)(pA0+SL+512+c4), C1A=*(const f16x4*)(pA0+SL+768+c4);
  f16x4 U1B=*(const f16x4*)(pB0+SL+256+c4), R1B=*(const f16x4*)(pB0+SL+512+c4), C1B=*(const f16x4*)(pB0+SL+768+c4);

  const f16* const wb = WsrF + (size_t)w * 32768;   // 8 ct-tiles * (8*64*8)

  lgkm_barrier();

  for (int i = 0; i < nsteps; ++i){
    const int t = t0 + i;
    const f16* ptS = P + (size_t)(i+2)*SL + (size_t)sgb*1792;
    const f16* ptA = P + (size_t)(i+2)*SL + (size_t)gbA*1792;
    const f16* ptB = P + (size_t)(i+2)*SL + (size_t)gbB*1792;

    // ---- phase 1: weights (2-deep pipe) + cold P loads + MFMA ----
    f32x4 acc[8];
    #pragma unroll
    for (int c = 0; c < 8; ++c) acc[c] = (f32x4){0.f,0.f,0.f,0.f};
    f16x8 wb0[8], wb1[8];
    #pragma unroll
    for (int c = 0; c < 8; ++c) wb0[c] = *(const f16x8*)(wb + ((c*8 + 0)*64 + l)*8);
    #pragma unroll
    for (int c = 0; c < 8; ++c) wb1[c] = *(const f16x8*)(wb + ((c*8 + 1)*64 + l)*8);

    // cold loads: slab i+2, each element of P touched exactly once per dispatch
    const f16x8 E2c = *(const f16x8*)(ptS + sc0);
    const f16x4 UcA=*(const f16x4*)(ptA+ 256+c4), RcA=*(const f16x4*)(ptA+ 512+c4), CcA=*(const f16x4*)(ptA+ 768+c4);
    const f16x4 NUA=*(const f16x4*)(ptA+1024+c4), NRA=*(const f16x4*)(ptA+1280+c4), NCA=*(const f16x4*)(ptA+1536+c4);
    const f16x4 UcB=*(const f16x4*)(ptB+ 256+c4), RcB=*(const f16x4*)(ptB+ 512+c4), CcB=*(const f16x4*)(ptB+ 768+c4);
    const f16x4 NUB=*(const f16x4*)(ptB+1024+c4), NRB=*(const f16x4*)(ptB+1280+c4), NCB=*(const f16x4*)(ptB+1536+c4);

    f16x8 av0 = *(const f16x8*)&stA[0*520 + l*8];
    f16x8 av1 = *(const f16x8*)&stA[1*520 + l*8];

    #pragma unroll
    for (int kt = 0; kt < 8; ++kt){
      f16x8 avc = (kt & 1) ? av1 : av0;
      if (kt < 6){
        f16x8 nx = *(const f16x8*)&stA[(kt+2)*520 + l*8];
        if (kt & 1) av1 = nx; else av0 = nx;
      }
      #pragma unroll
      for (int c = 0; c < 8; ++c){
        f16x8 cur = (kt & 1) ? wb1[c] : wb0[c];
        if (kt < 6){
          f16x8 nw = *(const f16x8*)(wb + ((c*8 + kt + 2)*64 + l)*8);
          if (kt & 1) wb1[c] = nw; else wb0[c] = nw;
        }
        acc[c] = mfma16(avc, cur, acc[c]);
      }
    }
    #pragma unroll
    for (int c = 0; c < 8; ++c){
      #pragma unroll
      for (int j = 0; j < 4; ++j)
        qg[(agrp*4 + j)*1026 + w*128 + c*16 + arow] = acc[c][j];
    }
    lgkm_barrier();

    // ---- phase 2: scores + softmax (half-wave per row) ----
    const float* qrow = &qg[srow*1026];
    const f32x4 q0 = *(const f32x4*)(qrow + sc0);
    const f32x4 q1 = *(const f32x4*)(qrow + sc0 + 4);
    float s0 = 0.f, s1 = 0.f, s2 = 0.f;
    #pragma unroll
    for (int j = 0; j < 8; ++j){
      const float qb = ((j < 4) ? q0[j] : q1[j-4]) + ((j < 4) ? sb0[j] : sb1[j-4]);
      const float lw = (j < 4) ? sl0[j] : sl1[j-4];
      s0 += tanh_f((float)E0[j]  + qb) * lw;
      s1 += tanh_f((float)E1[j]  + qb) * lw;
      s2 += tanh_f((float)E2c[j] + qb) * lw;
    }
    #pragma unroll
    for (int off = 16; off; off >>= 1){
      s0 += __shfl_xor(s0, off);
      s1 += __shfl_xor(s1, off);
      s2 += __shfl_xor(s2, off);
    }
    const float mx = fmaxf(fmaxf(s0, s1), s2);
    const float x0 = __expf(s0 - mx), x1 = __expf(s1 - mx), x2 = __expf(s2 - mx);
    const float inv = 1.0f / (x0 + x1 + x2);
    const float p0 = x0*inv, p1 = x1*inv, p2 = x2*inv;
    const float o0 = __shfl_xor(p0, 32), o1 = __shfl_xor(p1, 32), o2 = __shfl_xor(p2, 32);
    const bool lo = (l < 32);
    const float pA0_ = lo ? p0 : o0, pA1_ = lo ? p1 : o1, pA2_ = lo ? p2 : o2;
    const float pB0_ = lo ? o0 : p0, pB1_ = lo ? o1 : p1, pB2_ = lo ? o2 : p2;

    // ---- GRU for rows A and B (4 cols/lane, state in regs) ----
    const float* qA = &qg[rA*1026];
    const float* qB = &qg[rB*1026];
    const f32x4 quA=*(const f32x4*)(qA+256+c4), qrA=*(const f32x4*)(qA+512+c4), qcA=*(const f32x4*)(qA+768+c4);
    const f32x4 quB=*(const f32x4*)(qB+256+c4), qrB=*(const f32x4*)(qB+512+c4), qcB=*(const f32x4*)(qB+768+c4);
    #pragma unroll
    for (int j = 0; j < 4; ++j){
      const float geu = pA2_*(float)UcA[j] + pA1_*(float)U1A[j] + pA0_*(float)U2A[j];
      const float ger = pA2_*(float)RcA[j] + pA1_*(float)R1A[j] + pA0_*(float)R2A[j];
      const float gec = pA2_*(float)CcA[j] + pA1_*(float)C1A[j] + pA0_*(float)C2A[j];
      const float up   = sigmoid_f(quA[j] + geu + (float)NUA[j]);
      const float rp   = sigmoid_f(qrA[j] + ger + (float)NRA[j]);
      const float cand = tanh_f(rp*qcA[j] + gec + (float)NCA[j]);
      snA[j] = (1.0f - up)*snA[j] + up*cand;
    }
    #pragma unroll
    for (int j = 0; j < 4; ++j){
      const float geu = pB2_*(float)UcB[j] + pB1_*(float)U1B[j] + pB0_*(float)U2B[j];
      const float ger = pB2_*(float)RcB[j] + pB1_*(float)R1B[j] + pB0_*(float)R2B[j];
      const float gec = pB2_*(float)CcB[j] + pB1_*(float)C1B[j] + pB0_*(float)C2B[j];
      const float up   = sigmoid_f(quB[j] + geu + (float)NUB[j]);
      const float rp   = sigmoid_f(qrB[j] + ger + (float)NRB[j]);
      const float cand = tanh_f(rp*qcB[j] + gec + (float)NCB[j]);
      snB[j] = (1.0f - up)*snB[j] + up*cand;
    }
    { f16x4 h; h[0]=(f16)snA[0]; h[1]=(f16)snA[1]; h[2]=(f16)snA[2]; h[3]=(f16)snA[3]; *(f16x4*)saA = h; }
    { f16x4 h; h[0]=(f16)snB[0]; h[1]=(f16)snB[1]; h[2]=(f16)snB[2]; h[3]=(f16)snB[3]; *(f16x4*)saB = h; }
    if (t == 255){
      *(f32x4*)(out + (size_t)gbA*256 + c4) = snA;
      *(f32x4*)(out + (size_t)gbB*256 + c4) = snB;
    }
    // roll registers forward (slab i+1 -> "2-old", slab i+2 -> "1-old")
    E0 = E1; E1 = E2c;
    U2A=U1A; U1A=UcA; R2A=R1A; R1A=RcA; C2A=C1A; C1A=CcA;
    U2B=U1B; U1B=UcB; R2B=R1B; R1B=RcB; C2B=C1B; C1B=CcB;
    lgkm_barrier();
  }

  *(f32x4*)(state + (size_t)gbA*256 + c4) = snA;
  *(f32x4*)(state + (size_t)gbB*256 + c4) = snB;
}

// ---------------------------------- launch ----------------------------------
extern "C" void kernel_launch(void* const* d_in, const int* in_sizes, int n_in,
                              void* d_out, int out_size, void* d_ws, size_t ws_size,
                              hipStream_t stream)
{
  const float* X  = (const float*)d_in[0];
  const float* EK = (const float*)d_in[1];
  const float* SK = (const float*)d_in[2];
  const float* BI = (const float*)d_in[3];
  const float* LK = (const float*)d_in[4];
  const float* RS = (const float*)d_in[5];
  const float* RE = (const float*)d_in[6];
  const float* NW = (const float*)d_in[7];
  float* out = (float*)d_out;
  char* ws = (char*)d_ws;

  const size_t slabB = 1024ull * 1792ull * 2ull;   // 3,670,016 B
  const size_t XhB   = 134217728ull;               // 1024*256*256 f16
  const size_t wB    = 917504ull + 524288ull + 1048576ull;
  int CT = 4;
  if      (ws_size >= 18ull*slabB + XhB + wB) CT = 16;  // P chunk 66MB -> L3-resident
  else if (ws_size >= 10ull*slabB + XhB + wB) CT = 8;

  f16* P = (f16*)ws;
  size_t poff = (size_t)(CT + 2) * slabB;
  f16* Xh    = (f16*)(ws + poff);
  f16* WcatT = (f16*)(ws + poff + XhB);
  f16* WsrF  = (f16*)(ws + poff + XhB + 917504ull);
  float* state = (float*)(ws + poff + XhB + 917504ull + 524288ull);

  hipMemsetAsync(state, 0, 1048576ull, stream);
  hipMemsetAsync(P, 0, 2ull*slabB, stream);        // zero "virtual" slabs t=-2,-1
  cast_x_kernel<<<32768, 256, 0, stream>>>(X, Xh);
  cast_w_kernel<<<2816, 256, 0, stream>>>(EK, RE, NW, SK, RS, WcatT, WsrF);

  const int nch = 256 / CT;
  for (int c = 0; c < nch; ++c){
    const int t0 = c * CT;
    const int t_start  = (c == 0) ? 0 : (t0 - 2);
    const int slab_off = (c == 0) ? 2 : 0;
    const int Mtiles = (((c == 0) ? CT : (CT + 2)) * 1024) / 128;
    gemm_f16_kernel<<<Mtiles * 14, 256, 0, stream>>>(
        Xh, WcatT, P + (size_t)slab_off * 1024 * 1792, Mtiles, t_start);
    recurrent_kernel<<<64, 512, 0, stream>>>(P, WsrF, BI, LK, state, out, t0, CT);
  }
}

// Round 7
// 3060.297 us; speedup vs baseline: 1.3944x; 1.3944x over previous
//
#include <hip/hip_runtime.h>

// AttentionRNN: B=1024, T=256, U=256.
//  Xh = fp16(X); P[t] = x_t @ [Wemb|Wre|Wnew] (fp16 MFMA GEMM, CT=16 chunks, P L3-resident).
//  Recurrent: 128 blocks x 8 rows x 8 waves; wave w owns batch row r0+w.
//  qg = state @ [Wsk|Wrs] via MFMA with a register-resident 4-slot weight pipeline
//  (refills cross step boundaries; lgkm-only barriers keep them in flight).
//  P loads issued mid-phase-1 so in-order vmcnt retirement never gates weight use.
//  qg/bias/Lk use 9-word-group LDS layout (conflict-free stride-8 access).

typedef _Float16 f16;
typedef _Float16 f16x8 __attribute__((ext_vector_type(8)));
typedef _Float16 f16x4 __attribute__((ext_vector_type(4)));
typedef float f32x4 __attribute__((ext_vector_type(4)));

static __device__ __forceinline__ f32x4 mfma16(f16x8 a, f16x8 b, f32x4 c){
  return __builtin_amdgcn_mfma_f32_16x16x32_f16(a, b, c, 0, 0, 0);
}
static __device__ __forceinline__ float sigmoid_f(float x){
  return 1.0f / (1.0f + __expf(-x));
}
static __device__ __forceinline__ float tanh_f(float x){
  float e = __expf(2.0f * x);
  return 1.0f - 2.0f / (e + 1.0f);   // stable
}
// Block barrier draining LDS only; global loads stay in flight across it.
static __device__ __forceinline__ void lgkm_barrier(){
  asm volatile("s_waitcnt lgkmcnt(0)" ::: "memory");
  __builtin_amdgcn_s_barrier();
}

// ---------------- cast X fp32 -> fp16 (same layout) ----------------
__global__ void cast_x_kernel(const float* __restrict__ X, f16* __restrict__ Xh){
  size_t e = ((size_t)blockIdx.x * 256 + threadIdx.x) * 8;
  f32x4 v0 = *(const f32x4*)(X + e);
  f32x4 v1 = *(const f32x4*)(X + e + 4);
  f16x8 h;
  #pragma unroll
  for (int j = 0; j < 8; ++j) h[j] = (f16)((j < 4) ? v0[j] : v1[j-4]);
  *(f16x8*)(Xh + e) = h;
}

// ------------- cast weights to fp16 -------------
// WcatT rows: [0,256) Wemb^T, [256,1024) Wre^T, [1024,1792) Wnew^T  (N x K row-major)
// WsrF fragment-packed [ct64][kt8][lane64][e8]: col=ct*16+(lane&15), k=kt*32+((lane>>4)&3)*8+e
__global__ void cast_w_kernel(const float* __restrict__ EK, const float* __restrict__ RE,
    const float* __restrict__ NW, const float* __restrict__ SK, const float* __restrict__ RS,
    f16* __restrict__ WcatT, f16* __restrict__ WsrF){
  int tid = blockIdx.x * 256 + threadIdx.x;
  if (tid < 458752){
    int n = tid >> 8, k = tid & 255;
    float v;
    if (n < 256)       v = EK[k*256 + n];
    else if (n < 1024) v = RE[k*768 + (n-256)];
    else               v = NW[k*768 + (n-1024)];
    WcatT[n*256 + k] = (f16)v;
  } else {
    int idx = tid - 458752;            // 0..262143
    int e    = idx & 7;
    int lane = (idx >> 3) & 63;
    int kt   = (idx >> 9) & 7;
    int ct   = idx >> 12;              // 0..63
    int col  = ct*16 + (lane & 15);
    int k    = kt*32 + ((lane >> 4) & 3)*8 + e;
    float v = (col < 256) ? SK[k*256 + col] : RS[k*768 + (col-256)];
    WsrF[idx] = (f16)v;
  }
}

// ---- GEMM: C[r=tsl*1024+b][0:1792) = Xh[b][t_start+tsl][:] @ WcatT^T ----
__global__ __launch_bounds__(256, 2) void gemm_f16_kernel(
    const f16* __restrict__ Xh, const f16* __restrict__ Bm,
    f16* __restrict__ C, int Mtiles, int t_start)
{
  __shared__ f16 As[128*64];
  __shared__ f16 Bs[128*64];
  const int NT = 14;
  const int nwg = Mtiles * NT;
  int bid = blockIdx.x, wg = bid;
  if ((nwg & 7) == 0){ int cpx = nwg >> 3; wg = (bid & 7) * cpx + (bid >> 3); }
  const int mt = wg / NT, nt = wg % NT;
  const int tsl = mt >> 3;
  const int b0  = (mt & 7) * 128;
  const int t   = t_start + tsl;
  const int n0  = nt * 128;
  const int tid = threadIdx.x;
  const int l = tid & 63, wid = tid >> 6;
  const int wr = wid >> 1, wc = wid & 1;
  const int srow = tid >> 3;
  const int scol = (tid & 7) * 8;

  const size_t ASTR = 32ull * 65536ull;
  const f16* Ab = Xh + ((size_t)(b0 + srow) * 256 + t) * 256 + scol;
  const f16* Bb = Bm + ((size_t)(n0 + srow)) * 256 + scol;

  f16x8 ra[4], rb[4];
  #pragma unroll
  for (int j = 0; j < 4; ++j){
    ra[j] = *(const f16x8*)(Ab + (size_t)j * ASTR);
    rb[j] = *(const f16x8*)(Bb + (size_t)j * 32 * 256);
  }

  f32x4 acc[4][4];
  #pragma unroll
  for (int mi = 0; mi < 4; ++mi)
    #pragma unroll
    for (int ni = 0; ni < 4; ++ni)
      acc[mi][ni] = (f32x4){0.f,0.f,0.f,0.f};

  for (int kt = 0; kt < 4; ++kt){
    #pragma unroll
    for (int j = 0; j < 4; ++j){
      int row = srow + j*32;
      int e = (row*64 + scol) ^ ((row & 7) << 3);
      *(f16x8*)&As[e] = ra[j];
      *(f16x8*)&Bs[e] = rb[j];
    }
    __syncthreads();
    if (kt < 3){
      #pragma unroll
      for (int j = 0; j < 4; ++j){
        ra[j] = *(const f16x8*)(Ab + (kt+1)*64 + (size_t)j * ASTR);
        rb[j] = *(const f16x8*)(Bb + (kt+1)*64 + (size_t)j * 32 * 256);
      }
    }
    #pragma unroll
    for (int kk = 0; kk < 2; ++kk){
      f16x8 af[4], bfr[4];
      #pragma unroll
      for (int mi = 0; mi < 4; ++mi){
        int row = wr*64 + mi*16 + (l & 15);
        int e = (row*64 + kk*32 + (l >> 4)*8) ^ ((row & 7) << 3);
        af[mi] = *(const f16x8*)&As[e];
      }
      #pragma unroll
      for (int ni = 0; ni < 4; ++ni){
        int row = wc*64 + ni*16 + (l & 15);
        int e = (row*64 + kk*32 + (l >> 4)*8) ^ ((row & 7) << 3);
        bfr[ni] = *(const f16x8*)&Bs[e];
      }
      #pragma unroll
      for (int mi = 0; mi < 4; ++mi)
        #pragma unroll
        for (int ni = 0; ni < 4; ++ni)
          acc[mi][ni] = mfma16(af[mi], bfr[ni], acc[mi][ni]);
    }
    __syncthreads();
  }
  const size_t m0 = (size_t)mt * 128;
  #pragma unroll
  for (int mi = 0; mi < 4; ++mi){
    #pragma unroll
    for (int ni = 0; ni < 4; ++ni){
      int col = n0 + wc*64 + ni*16 + (l & 15);
      size_t row = m0 + wr*64 + mi*16 + ((l >> 4) * 4);
      #pragma unroll
      for (int j = 0; j < 4; ++j)
        C[(row + j) * 1792 + col] = (f16)acc[mi][ni][j];
    }
  }
}

// one kt-stage of the qg MFMA: 8 MFMAs, refill av (LDS) and this W slot (global).
// Refill address (KT+4)&7: for KT>=4 this is next step's kt0..3 (weights static).
template<int KT>
static __device__ __forceinline__ void stage(f32x4 (&acc)[8], f16x8 (&WS)[8], f16x8& av,
    const f16* stA_l, const f16* wb_l){
  #pragma unroll
  for (int c = 0; c < 8; ++c) acc[c] = mfma16(av, WS[c], acc[c]);
  if (KT < 6) av = *(const f16x8*)(stA_l + (KT+2)*520);
  #pragma unroll
  for (int c = 0; c < 8; ++c)
    WS[c] = *(const f16x8*)(wb_l + (c*8 + ((KT+4)&7))*512);
}

// ---------- recurrent: 128 blocks x 8 rows, 512 threads (8 waves) ----------
__global__ __launch_bounds__(512, 1) void recurrent_kernel(
    const f16* __restrict__ P, const f16* __restrict__ WsrF,
    const float* __restrict__ bias, const float* __restrict__ Lk,
    float* __restrict__ state, float* __restrict__ out,
    int t0, int nsteps)
{
  __shared__ float qg[8*1153];      // 8 rows, 9-word-group layout, stride 1153
  __shared__ f16  stA[8*520];       // state f16, fragment-major [kt][lane][8] + pad
  __shared__ float sb9[288], sl9[288];

  const int tid = threadIdx.x;
  const int l = tid & 63, w = tid >> 6;          // 8 waves, wave w owns row w
  const int r0 = blockIdx.x * 8;
  const int agrp = l >> 4;
  const int c4 = l * 4;                          // 4 cols/lane in [0,256)
  const int gb = r0 + w;
  const size_t SL = 1024ull*1792ull;

  // 9-word-group addressing
  const int qw_s  = (l >> 1)*9 + (l & 1)*4;      // word for col c4 within a row
  const int qgwr  = (w*16 + ((l & 15) >> 3))*9 + (l & 7);  // write: col part for c-tile 0

  if (tid < 256){ int wd = (tid >> 3)*9 + (tid & 7); sb9[wd] = bias[tid]; sl9[wd] = Lk[tid]; }
  for (int j = tid; j < 8*520; j += 512) stA[j] = (f16)0.f;
  __syncthreads();

  f32x4 sn = *(const f32x4*)(state + (size_t)gb*256 + c4);
  f16* const sa = &stA[(l >> 3)*520 + ((((l >> 1) & 3) << 4) + w)*8 + (l & 1)*4];
  { f16x4 h; h[0]=(f16)sn[0]; h[1]=(f16)sn[1]; h[2]=(f16)sn[2]; h[3]=(f16)sn[3]; *(f16x4*)sa = h; }

  const f16* const wb_l  = WsrF + (size_t)w*32768 + l*8;
  const f16* const stA_l = &stA[l*8];

  // prologue: fill 4 weight slots (kt 0..3)
  f16x8 W0[8], W1[8], W2[8], W3[8];
  #pragma unroll
  for (int c = 0; c < 8; ++c) W0[c] = *(const f16x8*)(wb_l + (c*8 + 0)*512);
  #pragma unroll
  for (int c = 0; c < 8; ++c) W1[c] = *(const f16x8*)(wb_l + (c*8 + 1)*512);
  #pragma unroll
  for (int c = 0; c < 8; ++c) W2[c] = *(const f16x8*)(wb_l + (c*8 + 2)*512);
  #pragma unroll
  for (int c = 0; c < 8; ++c) W3[c] = *(const f16x8*)(wb_l + (c*8 + 3)*512);
  __syncthreads();

  for (int i = 0; i < nsteps; ++i){
    const int t = t0 + i;
    const f16* p2 = P + (size_t)(i+2)*SL + (size_t)gb*1792;
    const f16* p1 = P + (size_t)(i+1)*SL + (size_t)gb*1792;
    const f16* p0 = P + (size_t)(i+0)*SL + (size_t)gb*1792;

    f16x8 av0 = *(const f16x8*)(stA_l + 0*520);
    f16x8 av1 = *(const f16x8*)(stA_l + 1*520);
    f32x4 acc[8];
    #pragma unroll
    for (int c = 0; c < 8; ++c) acc[c] = (f32x4){0.f,0.f,0.f,0.f};

    stage<0>(acc, W0, av0, stA_l, wb_l);
    stage<1>(acc, W1, av1, stA_l, wb_l);
    stage<2>(acc, W2, av0, stA_l, wb_l);
    stage<3>(acc, W3, av1, stA_l, wb_l);

    // P loads for this step (issued AFTER stages 0-3's weight refills so in-order
    // vmcnt retirement never makes stage 4-7 wait on these slower loads)
    const f16x4 E2 = *(const f16x4*)(p2 + c4);
    const f16x4 E1 = *(const f16x4*)(p1 + c4);
    const f16x4 E0 = *(const f16x4*)(p0 + c4);
    const f16x4 Uc = *(const f16x4*)(p2 +  256 + c4);
    const f16x4 Rc = *(const f16x4*)(p2 +  512 + c4);
    const f16x4 Cc = *(const f16x4*)(p2 +  768 + c4);
    const f16x4 NU = *(const f16x4*)(p2 + 1024 + c4);
    const f16x4 NR = *(const f16x4*)(p2 + 1280 + c4);
    const f16x4 NC = *(const f16x4*)(p2 + 1536 + c4);
    const f16x4 U1 = *(const f16x4*)(p1 +  256 + c4);
    const f16x4 R1 = *(const f16x4*)(p1 +  512 + c4);
    const f16x4 C1 = *(const f16x4*)(p1 +  768 + c4);
    const f16x4 U2 = *(const f16x4*)(p0 +  256 + c4);
    const f16x4 R2 = *(const f16x4*)(p0 +  512 + c4);
    const f16x4 C2 = *(const f16x4*)(p0 +  768 + c4);

    stage<4>(acc, W0, av0, stA_l, wb_l);
    stage<5>(acc, W1, av1, stA_l, wb_l);
    stage<6>(acc, W2, av0, stA_l, wb_l);
    stage<7>(acc, W3, av1, stA_l, wb_l);

    // qg write: C-layout row = agrp*4+j (keep rows 0..7 only), col = w*128+c*16+(l&15)
    if (agrp < 2){
      #pragma unroll
      for (int c = 0; c < 8; ++c){
        #pragma unroll
        for (int j = 0; j < 4; ++j)
          qg[(agrp*4 + j)*1153 + qgwr + c*18] = acc[c][j];
      }
    }
    lgkm_barrier();

    // ---- phase 2: scores + softmax (full wave on row w) ----
    const float* qrow = &qg[w*1153];
    const f32x4 q  = *(const f32x4*)(qrow + qw_s);
    const f32x4 bb = *(const f32x4*)(sb9 + qw_s);
    const f32x4 lk = *(const f32x4*)(sl9 + qw_s);
    float s0 = 0.f, s1 = 0.f, s2 = 0.f;
    #pragma unroll
    for (int j = 0; j < 4; ++j){
      const float qb = q[j] + bb[j];
      s0 += tanh_f((float)E0[j] + qb) * lk[j];
      s1 += tanh_f((float)E1[j] + qb) * lk[j];
      s2 += tanh_f((float)E2[j] + qb) * lk[j];
    }
    #pragma unroll
    for (int off = 32; off; off >>= 1){
      s0 += __shfl_xor(s0, off);
      s1 += __shfl_xor(s1, off);
      s2 += __shfl_xor(s2, off);
    }
    const float mx = fmaxf(fmaxf(s0, s1), s2);
    const float x0 = __expf(s0 - mx), x1 = __expf(s1 - mx), x2 = __expf(s2 - mx);
    const float inv = 1.0f / (x0 + x1 + x2);
    const float pr0 = x0*inv, pr1 = x1*inv, pr2 = x2*inv;

    // ---- GRU (row w, 4 cols/lane, state in regs) ----
    const f32x4 qu = *(const f32x4*)(qrow + (32 + (l >> 1))*9 + (l & 1)*4);
    const f32x4 qr = *(const f32x4*)(qrow + (64 + (l >> 1))*9 + (l & 1)*4);
    const f32x4 qc = *(const f32x4*)(qrow + (96 + (l >> 1))*9 + (l & 1)*4);
    #pragma unroll
    for (int j = 0; j < 4; ++j){
      const float geu = pr2*(float)Uc[j] + pr1*(float)U1[j] + pr0*(float)U2[j];
      const float ger = pr2*(float)Rc[j] + pr1*(float)R1[j] + pr0*(float)R2[j];
      const float gec = pr2*(float)Cc[j] + pr1*(float)C1[j] + pr0*(float)C2[j];
      const float up   = sigmoid_f(qu[j] + geu + (float)NU[j]);
      const float rp   = sigmoid_f(qr[j] + ger + (float)NR[j]);
      const float cand = tanh_f(rp*qc[j] + gec + (float)NC[j]);
      sn[j] = (1.0f - up)*sn[j] + up*cand;
    }
    { f16x4 h; h[0]=(f16)sn[0]; h[1]=(f16)sn[1]; h[2]=(f16)sn[2]; h[3]=(f16)sn[3]; *(f16x4*)sa = h; }
    if (t == 255) *(f32x4*)(out + (size_t)gb*256 + c4) = sn;
    lgkm_barrier();
  }

  *(f32x4*)(state + (size_t)gb*256 + c4) = sn;
}

// ---------------------------------- launch ----------------------------------
extern "C" void kernel_launch(void* const* d_in, const int* in_sizes, int n_in,
                              void* d_out, int out_size, void* d_ws, size_t ws_size,
                              hipStream_t stream)
{
  const float* X  = (const float*)d_in[0];
  const float* EK = (const float*)d_in[1];
  const float* SK = (const float*)d_in[2];
  const float* BI = (const float*)d_in[3];
  const float* LK = (const float*)d_in[4];
  const float* RS = (const float*)d_in[5];
  const float* RE = (const float*)d_in[6];
  const float* NW = (const float*)d_in[7];
  float* out = (float*)d_out;
  char* ws = (char*)d_ws;

  const size_t slabB = 1024ull * 1792ull * 2ull;   // 3,670,016 B
  const size_t XhB   = 134217728ull;               // 1024*256*256 f16
  const size_t wB    = 917504ull + 524288ull + 1048576ull;
  int CT = 4;
  if      (ws_size >= 18ull*slabB + XhB + wB) CT = 16;  // P chunk 66MB -> L3-resident
  else if (ws_size >= 10ull*slabB + XhB + wB) CT = 8;

  f16* P = (f16*)ws;
  size_t poff = (size_t)(CT + 2) * slabB;
  f16* Xh    = (f16*)(ws + poff);
  f16* WcatT = (f16*)(ws + poff + XhB);
  f16* WsrF  = (f16*)(ws + poff + XhB + 917504ull);
  float* state = (float*)(ws + poff + XhB + 917504ull + 524288ull);

  hipMemsetAsync(state, 0, 1048576ull, stream);
  hipMemsetAsync(P, 0, 2ull*slabB, stream);        // zero "virtual" slabs t=-2,-1
  cast_x_kernel<<<32768, 256, 0, stream>>>(X, Xh);
  cast_w_kernel<<<2816, 256, 0, stream>>>(EK, RE, NW, SK, RS, WcatT, WsrF);

  const int nch = 256 / CT;
  for (int c = 0; c < nch; ++c){
    const int t0 = c * CT;
    const int t_start  = (c == 0) ? 0 : (t0 - 2);
    const int slab_off = (c == 0) ? 2 : 0;
    const int Mtiles = (((c == 0) ? CT : (CT + 2)) * 1024) / 128;
    gemm_f16_kernel<<<Mtiles * 14, 256, 0, stream>>>(
        Xh, WcatT, P + (size_t)slab_off * 1024 * 1792, Mtiles, t_start);
    recurrent_kernel<<<128, 512, 0, stream>>>(P, WsrF, BI, LK, state, out, t0, CT);
  }
}